// Round 4
// baseline (609.909 us; speedup 1.0000x reference)
//
#include <hip/hip_runtime.h>

// OPU via MFMA, R4: 128x128 tiles + K-split x4 + XCD swizzle + coalesced presplit.
// presplit: a = fl(x + vlut[k%16][x+8]) (resp. w) split into f16 hi/lo (a = ah+al+eps),
// stored in global memory in MFMA-fragment order:
//   XH/XL[mblk16][chunk64][rg4][oct2][row32][k8] u16  (4KB per (mblk,chunk))
//   WH/WL[nblk8][chunk64][ng4][oct2][n32][k8]   u16
// main: 512 blocks = 8 nblk x 16 mblk x 4 kslice (2/CU), 512 thr = 8 waves.
// Wave owns 32x64 of the 128x128 out tile; per chunk: 6 ds_read_b128 + 6 MFMA
// (AhBh + AlBh + AhBl per 32x32 tile; AlBl dropped, |err| <= 4e-6 of rint grid)
// + ADC quant (mul 1/16, rndne, med3, add). Stage = 2 chunks = 32KB, double-buffered
// 64KB LDS, staged by global_load_lds_dwordx4 (1 wave = 1 plane segment), 9 barriers.
// Integer-valued partials to ws; reduce4 kernel: out = 16*(p0+p1+p2+p3).
// Block swizzle: linear b%8 = (mblk*4+ks)%8 -> A-sharing siblings on same XCD.

typedef unsigned int u32;
typedef unsigned short u16;
typedef _Float16 f16x8 __attribute__((ext_vector_type(8)));
typedef float f32x16 __attribute__((ext_vector_type(16)));

#define M_TOT 2048
#define N_TOT 1024
#define K_TOT 1024

__device__ __forceinline__ void gload_lds16(const void* g, void* l) {
  __builtin_amdgcn_global_load_lds(
      (const __attribute__((address_space(1))) void*)g,
      (__attribute__((address_space(3))) void*)l, 16, 0, 0);
}

__global__ __launch_bounds__(256) void presplit(
    const float* __restrict__ x, const float* __restrict__ w,
    const float* __restrict__ vl, const float* __restrict__ wl,
    u16* __restrict__ XH, u16* __restrict__ XL,
    u16* __restrict__ WH, u16* __restrict__ WL)
{
  const int b = blockIdx.x;
  if (b < 512) {
    // X: lane runs along k -> wave reads 4KB contiguous (coalesced).
    const int g = b * 256 + threadIdx.x;
    const int ch = g & 63, m = g >> 6;
    const int mblk = m >> 7, rg = (m >> 5) & 3, row = m & 31;
    const float* xp = x + (size_t)m * K_TOT + ch * 16;
    u32 hp[8], lp[8];
#pragma unroll
    for (int e2 = 0; e2 < 8; ++e2) {
      u16 h2[2], l2[2];
#pragma unroll
      for (int q = 0; q < 2; ++q) {
        const int e = e2 * 2 + q;
        const float v = xp[e];
        const int xi = (int)(v + 8.0f);          // x always in [-8,7]
        const float a = v + vl[e * 16 + xi];     // j = k%16 = e (chunk-aligned)
        const _Float16 h = (_Float16)a;
        const _Float16 l = (_Float16)(a - (float)h);
        h2[q] = __builtin_bit_cast(u16, h);
        l2[q] = __builtin_bit_cast(u16, l);
      }
      hp[e2] = (u32)h2[0] | ((u32)h2[1] << 16);
      lp[e2] = (u32)l2[0] | ((u32)l2[1] << 16);
    }
    const size_t base = (size_t)(mblk * 64 + ch) * 2048 + rg * 512 + row * 8;
    *(uint4*)&XH[base]       = make_uint4(hp[0], hp[1], hp[2], hp[3]);  // oct0
    *(uint4*)&XH[base + 256] = make_uint4(hp[4], hp[5], hp[6], hp[7]);  // oct1
    *(uint4*)&XL[base]       = make_uint4(lp[0], lp[1], lp[2], lp[3]);
    *(uint4*)&XL[base + 256] = make_uint4(lp[4], lp[5], lp[6], lp[7]);
  } else {
    // W: lane runs along n -> each k-row read is 256B contiguous per wave.
    const int g = (b - 512) * 256 + threadIdx.x;
    const int n = g & 1023, ch = g >> 10;
    const int nblk = n >> 7, ng = (n >> 5) & 3, n32 = n & 31;
    const float* wp = w + (size_t)(ch * 16) * N_TOT + n;
    u32 hp[8], lp[8];
#pragma unroll
    for (int e2 = 0; e2 < 8; ++e2) {
      u16 h2[2], l2[2];
#pragma unroll
      for (int q = 0; q < 2; ++q) {
        const int e = e2 * 2 + q;
        const float v = wp[(size_t)e * N_TOT];
        const int wi = (int)(v + 8.0f);
        const float a = v + wl[e * 16 + wi];
        const _Float16 h = (_Float16)a;
        const _Float16 l = (_Float16)(a - (float)h);
        h2[q] = __builtin_bit_cast(u16, h);
        l2[q] = __builtin_bit_cast(u16, l);
      }
      hp[e2] = (u32)h2[0] | ((u32)h2[1] << 16);
      lp[e2] = (u32)l2[0] | ((u32)l2[1] << 16);
    }
    const size_t base = (size_t)(nblk * 64 + ch) * 2048 + ng * 512 + n32 * 8;
    *(uint4*)&WH[base]       = make_uint4(hp[0], hp[1], hp[2], hp[3]);
    *(uint4*)&WH[base + 256] = make_uint4(hp[4], hp[5], hp[6], hp[7]);
    *(uint4*)&WL[base]       = make_uint4(lp[0], lp[1], lp[2], lp[3]);
    *(uint4*)&WL[base + 256] = make_uint4(lp[4], lp[5], lp[6], lp[7]);
  }
}

__global__ __launch_bounds__(512, 4) void opu_main(
    const u16* __restrict__ XH, const u16* __restrict__ XL,
    const u16* __restrict__ WH, const u16* __restrict__ WL,
    float* __restrict__ partials)
{
  // [buf2][ Ah c0|c1 8KB | Al 8KB | Bh 8KB | Bl 8KB ]
  __shared__ __align__(16) char smem[2][32768];

  const int tid  = threadIdx.x;
  const int wave = tid >> 6;
  const int lane = tid & 63;
  const int oct  = lane >> 5;
  const int ll   = lane & 31;
  const int wm   = wave >> 1;   // row-group 0..3 (32 rows each)
  const int wn   = wave & 1;    // col-half (64 cols each)

  const int bx   = blockIdx.x;
  const int nblk = bx >> 6;            // 0..7
  const int rem  = bx & 63;
  const int mblk = rem >> 2;           // 0..15
  const int ks   = rem & 3;            // k-slice: chunks ks*16 .. ks*16+15
  // bx % 8 == (mblk*4+ks)%8 -> the 8 nblk-siblings (sharing A) map to one XCD.

  // DMA role: wave = plane segment [Ah c0, Ah c1, Al c0, Al c1, Bh c0, Bh c1, Bl c0, Bl c1]
  const int kind = wave >> 1, segc = wave & 1;
  const char* gsrc;
  if      (kind == 0) gsrc = (const char*)XH + (size_t)mblk * 64 * 4096;
  else if (kind == 1) gsrc = (const char*)XL + (size_t)mblk * 64 * 4096;
  else if (kind == 2) gsrc = (const char*)WH + (size_t)nblk * 64 * 4096;
  else                gsrc = (const char*)WL + (size_t)nblk * 64 * 4096;
  gsrc += (size_t)(ks * 16 + segc) * 4096 + lane * 16;

  // stage 0 -> buf 0
#pragma unroll
  for (int i = 0; i < 4; ++i)
    gload_lds16(gsrc + i * 1024, smem[0] + wave * 4096 + i * 1024);
  __syncthreads();

  float res[2][16];
#pragma unroll
  for (int t = 0; t < 2; ++t)
#pragma unroll
    for (int i = 0; i < 16; ++i) res[t][i] = 0.0f;
  const f32x16 fzero = {};

  const int aoff = wm * 1024 + oct * 512 + ll * 16;
  const int boff = oct * 512 + ll * 16;

#pragma unroll
  for (int s = 0; s < 8; ++s) {
    char* cur = smem[s & 1];
    if (s < 7) {
      char* nxt = smem[(s & 1) ^ 1];
#pragma unroll
      for (int i = 0; i < 4; ++i)
        gload_lds16(gsrc + (size_t)(s + 1) * 8192 + i * 1024,
                    nxt + wave * 4096 + i * 1024);
    }
#pragma unroll
    for (int cc = 0; cc < 2; ++cc) {
      const f16x8 Ah = *(const f16x8*)(cur + cc * 4096 + aoff);
      const f16x8 Al = *(const f16x8*)(cur + 8192 + cc * 4096 + aoff);
#pragma unroll
      for (int t = 0; t < 2; ++t) {
        const int bo = cc * 4096 + (wn * 2 + t) * 1024 + boff;
        const f16x8 Bh = *(const f16x8*)(cur + 16384 + bo);
        const f16x8 Bl = *(const f16x8*)(cur + 24576 + bo);
        f32x16 acc = __builtin_amdgcn_mfma_f32_32x32x16_f16(Ah, Bh, fzero, 0, 0, 0);
        acc = __builtin_amdgcn_mfma_f32_32x32x16_f16(Al, Bh, acc, 0, 0, 0);
        acc = __builtin_amdgcn_mfma_f32_32x32x16_f16(Ah, Bl, acc, 0, 0, 0);
#pragma unroll
        for (int i = 0; i < 16; ++i) {
          float r = __builtin_rintf(acc[i] * 0.0625f);     // v_rndne (ties-to-even)
          r = __builtin_amdgcn_fmed3f(r, -128.0f, 127.0f); // clip
          res[t][i] += r;
        }
      }
    }
    __syncthreads();
  }

  // integer-valued partial sums -> ws
  float* pp = partials + (size_t)ks * (M_TOT * N_TOT);
  const int grow = mblk * 128 + wm * 32;
  const int gcol = nblk * 128 + wn * 64 + ll;
#pragma unroll
  for (int t = 0; t < 2; ++t)
#pragma unroll
    for (int i = 0; i < 16; ++i) {
      const int rr = (i & 3) + 8 * (i >> 2) + 4 * oct;  // verified C/D layout
      pp[(size_t)(grow + rr) * N_TOT + gcol + t * 32] = res[t][i];
    }
}

__global__ __launch_bounds__(256) void reduce4(const float4* __restrict__ p,
                                               float4* __restrict__ out)
{
  const int i = blockIdx.x * 256 + threadIdx.x;     // 512K float4
  const float4 a = p[i];
  const float4 b = p[i + 524288];
  const float4 c = p[i + 2 * 524288];
  const float4 d = p[i + 3 * 524288];
  float4 o;
  o.x = 16.0f * (a.x + b.x + c.x + d.x);
  o.y = 16.0f * (a.y + b.y + c.y + d.y);
  o.z = 16.0f * (a.z + b.z + c.z + d.z);
  o.w = 16.0f * (a.w + b.w + c.w + d.w);
  out[i] = o;
}

extern "C" void kernel_launch(void* const* d_in, const int* in_sizes, int n_in,
                              void* d_out, int out_size, void* d_ws, size_t ws_size,
                              hipStream_t stream)
{
  const float* input  = (const float*)d_in[0];
  const float* weight = (const float*)d_in[1];
  const float* vmap   = (const float*)d_in[2];
  const float* wmap   = (const float*)d_in[3];

  u16* XH = (u16*)d_ws;                          // 4MB (2M u16)
  u16* XL = XH + 2 * 1024 * 1024;                // 4MB
  u16* WH = XL + 2 * 1024 * 1024;                // 2MB
  u16* WL = WH + 1024 * 1024;                    // 2MB
  float* partials = (float*)((char*)d_ws + 12 * 1024 * 1024);  // 4 x 8MB

  presplit<<<768, 256, 0, stream>>>(input, weight, vmap, wmap, XH, XL, WH, WL);

  opu_main<<<512, 512, 0, stream>>>(XH, XL, WH, WL, partials);

  reduce4<<<2048, 256, 0, stream>>>((const float4*)partials, (float4*)d_out);
}

// Round 5
// 104.503 us; speedup vs baseline: 5.8363x; 5.8363x over previous
//
#include <hip/hip_runtime.h>

// OPU via MFMA, R5 = R4 traffic structure with spill-free registers.
// presplit: a = fl(x + vlut[k%16][x+8]) (resp. w) split into f16 hi/lo (a = ah+al+eps),
// stored in global memory in MFMA-fragment order:
//   XH/XL[mblk16][chunk64][rg4][oct2][row32][k8] u16  (4KB per (mblk,chunk))
//   WH/WL[nblk8][chunk64][ng4][oct2][n32][k8]   u16
// main: 512 blocks = 8 nblk x 16 mblk x 4 kslice (2/CU), 256 thr = 4 waves,
// __launch_bounds__(256,2) -> 256-VGPR budget (R4's (512,4) capped at 128 and SPILLED:
// 2GB scratch traffic, MfmaUtil 1%). Wave owns a 64x64 quadrant: res[4][16] (64 VGPR).
// Per chunk per wave: 8 ds_read_b128 -> 12 MFMA (AhBh+AlBh+AhBl per 32x32; AlBl dropped,
// |err|<=4e-6 of rint grid) + ADC quant (mul 1/16, rndne, med3, add).
// Stage = 2 chunks = 32KB, double-buffered 64KB LDS; wave w DMAs plane kind w
// (8KB contiguous global -> contiguous LDS) via global_load_lds_dwordx4; 1 barrier/stage.
// Integer partials to ws; reduce4: out = 16*(p0+p1+p2+p3).
// Swizzle: bx%8 = (mblk*4+ks)%8 -> A-sharing siblings land on one XCD (L2-resident planes).

typedef unsigned int u32;
typedef unsigned short u16;
typedef _Float16 f16x8 __attribute__((ext_vector_type(8)));
typedef float f32x16 __attribute__((ext_vector_type(16)));

#define M_TOT 2048
#define N_TOT 1024
#define K_TOT 1024

__device__ __forceinline__ void gload_lds16(const void* g, void* l) {
  __builtin_amdgcn_global_load_lds(
      (const __attribute__((address_space(1))) void*)g,
      (__attribute__((address_space(3))) void*)l, 16, 0, 0);
}

__global__ __launch_bounds__(256) void presplit(
    const float* __restrict__ x, const float* __restrict__ w,
    const float* __restrict__ vl, const float* __restrict__ wl,
    u16* __restrict__ XH, u16* __restrict__ XL,
    u16* __restrict__ WH, u16* __restrict__ WL)
{
  const int b = blockIdx.x;
  if (b < 512) {
    // X: lane runs along k -> wave reads 4KB contiguous (coalesced).
    const int g = b * 256 + threadIdx.x;
    const int ch = g & 63, m = g >> 6;
    const int mblk = m >> 7, rg = (m >> 5) & 3, row = m & 31;
    const float* xp = x + (size_t)m * K_TOT + ch * 16;
    u32 hp[8], lp[8];
#pragma unroll
    for (int e2 = 0; e2 < 8; ++e2) {
      u16 h2[2], l2[2];
#pragma unroll
      for (int q = 0; q < 2; ++q) {
        const int e = e2 * 2 + q;
        const float v = xp[e];
        const int xi = (int)(v + 8.0f);          // x always in [-8,7]
        const float a = v + vl[e * 16 + xi];     // j = k%16 = e (chunk-aligned)
        const _Float16 h = (_Float16)a;
        const _Float16 l = (_Float16)(a - (float)h);
        h2[q] = __builtin_bit_cast(u16, h);
        l2[q] = __builtin_bit_cast(u16, l);
      }
      hp[e2] = (u32)h2[0] | ((u32)h2[1] << 16);
      lp[e2] = (u32)l2[0] | ((u32)l2[1] << 16);
    }
    const size_t base = (size_t)(mblk * 64 + ch) * 2048 + rg * 512 + row * 8;
    *(uint4*)&XH[base]       = make_uint4(hp[0], hp[1], hp[2], hp[3]);  // oct0
    *(uint4*)&XH[base + 256] = make_uint4(hp[4], hp[5], hp[6], hp[7]);  // oct1
    *(uint4*)&XL[base]       = make_uint4(lp[0], lp[1], lp[2], lp[3]);
    *(uint4*)&XL[base + 256] = make_uint4(lp[4], lp[5], lp[6], lp[7]);
  } else {
    // W: lane runs along n -> each k-row read is 256B contiguous per wave.
    const int g = (b - 512) * 256 + threadIdx.x;
    const int n = g & 1023, ch = g >> 10;
    const int nblk = n >> 7, ng = (n >> 5) & 3, n32 = n & 31;
    const float* wp = w + (size_t)(ch * 16) * N_TOT + n;
    u32 hp[8], lp[8];
#pragma unroll
    for (int e2 = 0; e2 < 8; ++e2) {
      u16 h2[2], l2[2];
#pragma unroll
      for (int q = 0; q < 2; ++q) {
        const int e = e2 * 2 + q;
        const float v = wp[(size_t)e * N_TOT];
        const int wi = (int)(v + 8.0f);
        const float a = v + wl[e * 16 + wi];
        const _Float16 h = (_Float16)a;
        const _Float16 l = (_Float16)(a - (float)h);
        h2[q] = __builtin_bit_cast(u16, h);
        l2[q] = __builtin_bit_cast(u16, l);
      }
      hp[e2] = (u32)h2[0] | ((u32)h2[1] << 16);
      lp[e2] = (u32)l2[0] | ((u32)l2[1] << 16);
    }
    const size_t base = (size_t)(nblk * 64 + ch) * 2048 + ng * 512 + n32 * 8;
    *(uint4*)&WH[base]       = make_uint4(hp[0], hp[1], hp[2], hp[3]);
    *(uint4*)&WH[base + 256] = make_uint4(hp[4], hp[5], hp[6], hp[7]);
    *(uint4*)&WL[base]       = make_uint4(lp[0], lp[1], lp[2], lp[3]);
    *(uint4*)&WL[base + 256] = make_uint4(lp[4], lp[5], lp[6], lp[7]);
  }
}

__global__ __launch_bounds__(256, 2) void opu_main(
    const u16* __restrict__ XH, const u16* __restrict__ XL,
    const u16* __restrict__ WH, const u16* __restrict__ WL,
    float* __restrict__ partials)
{
  // [buf2][kind4: Ah|Al|Bh|Bl][chunk2][4KB] = 64KB
  __shared__ __align__(16) char smem[2][32768];

  const int tid  = threadIdx.x;
  const int wave = tid >> 6;    // = plane kind for DMA; (wm,wn) for compute
  const int lane = tid & 63;
  const int oct  = lane >> 5;
  const int ll   = lane & 31;
  const int wm   = wave >> 1;   // m-half of 128x128 tile (64 rows)
  const int wn   = wave & 1;    // n-half (64 cols)

  const int bx   = blockIdx.x;
  const int nblk = bx >> 6;            // 0..7
  const int rem  = bx & 63;
  const int mblk = rem >> 2;           // 0..15
  const int ks   = rem & 3;            // chunks ks*16 .. ks*16+15
  // bx % 8 == (mblk*4+ks)%8 -> the 8 nblk-siblings (sharing A planes) on one XCD.

  // DMA role: wave w stages plane kind w (2 chunks = 8KB contiguous global).
  const char* gsrc;
  if      (wave == 0) gsrc = (const char*)XH + (size_t)mblk * 64 * 4096;
  else if (wave == 1) gsrc = (const char*)XL + (size_t)mblk * 64 * 4096;
  else if (wave == 2) gsrc = (const char*)WH + (size_t)nblk * 64 * 4096;
  else                gsrc = (const char*)WL + (size_t)nblk * 64 * 4096;
  gsrc += (size_t)(ks * 16) * 4096 + lane * 16;

  // stage 0 -> buf 0
#pragma unroll
  for (int i = 0; i < 8; ++i)
    gload_lds16(gsrc + i * 1024, smem[0] + wave * 8192 + i * 1024);
  __syncthreads();

  float res[4][16];
#pragma unroll
  for (int t = 0; t < 4; ++t)
#pragma unroll
    for (int i = 0; i < 16; ++i) res[t][i] = 0.0f;
  const f32x16 fzero = {};

  const int lsub = oct * 512 + ll * 16;

  for (int s = 0; s < 8; ++s) {
    char* cur = smem[s & 1];
    if (s < 7) {
      char* nxt = smem[(s & 1) ^ 1];
#pragma unroll
      for (int i = 0; i < 8; ++i)
        gload_lds16(gsrc + (size_t)(s + 1) * 8192 + i * 1024,
                    nxt + wave * 8192 + i * 1024);
    }
#pragma unroll
    for (int c = 0; c < 2; ++c) {
      const char* cb = cur + c * 4096;
      f16x8 Ah[2], Al[2], Bh[2], Bl[2];
#pragma unroll
      for (int t = 0; t < 2; ++t) {
        const int ao = (2 * wm + t) * 1024 + lsub;
        const int bo = (2 * wn + t) * 1024 + lsub;
        Ah[t] = *(const f16x8*)(cb + ao);
        Al[t] = *(const f16x8*)(cb + 8192 + ao);
        Bh[t] = *(const f16x8*)(cb + 16384 + bo);
        Bl[t] = *(const f16x8*)(cb + 24576 + bo);
      }
#pragma unroll
      for (int mt = 0; mt < 2; ++mt)
#pragma unroll
        for (int nt = 0; nt < 2; ++nt) {
          f32x16 acc = __builtin_amdgcn_mfma_f32_32x32x16_f16(Ah[mt], Bh[nt], fzero, 0, 0, 0);
          acc = __builtin_amdgcn_mfma_f32_32x32x16_f16(Al[mt], Bh[nt], acc, 0, 0, 0);
          acc = __builtin_amdgcn_mfma_f32_32x32x16_f16(Ah[mt], Bl[nt], acc, 0, 0, 0);
          float* r4 = res[mt * 2 + nt];
#pragma unroll
          for (int i = 0; i < 16; ++i) {
            float r = __builtin_rintf(acc[i] * 0.0625f);     // v_rndne (ties-to-even)
            r = __builtin_amdgcn_fmed3f(r, -128.0f, 127.0f); // clip
            r4[i] += r;
          }
        }
    }
    __syncthreads();  // drains next-stage DMA; all reads of cur done block-wide
  }

  // integer-valued partial sums -> ws
  float* pp = partials + (size_t)ks * (M_TOT * N_TOT);
  const int grow = mblk * 128 + wm * 64;
  const int gcol = nblk * 128 + wn * 64 + ll;
#pragma unroll
  for (int mt = 0; mt < 2; ++mt)
#pragma unroll
    for (int nt = 0; nt < 2; ++nt)
#pragma unroll
      for (int i = 0; i < 16; ++i) {
        const int rr = (i & 3) + 8 * (i >> 2) + 4 * oct;  // verified C/D layout
        pp[(size_t)(grow + mt * 32 + rr) * N_TOT + gcol + nt * 32] = res[mt * 2 + nt][i];
      }
}

__global__ __launch_bounds__(256) void reduce4(const float4* __restrict__ p,
                                               float4* __restrict__ out)
{
  const int i = blockIdx.x * 256 + threadIdx.x;     // 512K float4
  const float4 a = p[i];
  const float4 b = p[i + 524288];
  const float4 c = p[i + 2 * 524288];
  const float4 d = p[i + 3 * 524288];
  float4 o;
  o.x = 16.0f * (a.x + b.x + c.x + d.x);
  o.y = 16.0f * (a.y + b.y + c.y + d.y);
  o.z = 16.0f * (a.z + b.z + c.z + d.z);
  o.w = 16.0f * (a.w + b.w + c.w + d.w);
  out[i] = o;
}

extern "C" void kernel_launch(void* const* d_in, const int* in_sizes, int n_in,
                              void* d_out, int out_size, void* d_ws, size_t ws_size,
                              hipStream_t stream)
{
  const float* input  = (const float*)d_in[0];
  const float* weight = (const float*)d_in[1];
  const float* vmap   = (const float*)d_in[2];
  const float* wmap   = (const float*)d_in[3];

  u16* XH = (u16*)d_ws;                          // 4MB (2M u16)
  u16* XL = XH + 2 * 1024 * 1024;                // 4MB
  u16* WH = XL + 2 * 1024 * 1024;                // 2MB
  u16* WL = WH + 1024 * 1024;                    // 2MB
  float* partials = (float*)((char*)d_ws + 12 * 1024 * 1024);  // 4 x 8MB

  presplit<<<768, 256, 0, stream>>>(input, weight, vmap, wmap, XH, XL, WH, WL);

  opu_main<<<512, 256, 0, stream>>>(XH, XL, WH, WL, partials);

  reduce4<<<2048, 256, 0, stream>>>((const float4*)partials, (float4*)d_out);
}

// Round 6
// 97.993 us; speedup vs baseline: 6.2240x; 1.0664x over previous
//
#include <hip/hip_runtime.h>

// OPU via MFMA, R6: barrier-free main loop with direct global->register fragment loads.
// presplit: a = fl(x + vlut[k%16][x+8]); b = fl(w + wlut[k%16][w+8]) * (1/16)  (exact pow2
// scale folded into B so acc = mm/16 and quant is 3 VALU ops). Both split into f16 hi/lo
// (a = ah+al+eps, |eps|<=2^-19) and stored in global memory in MFMA-fragment order:
//   XH/XL[mblk16][chunk64][rg4][oct2][row32][k8] u16  (4KB per (mblk,chunk); 1KB per rg)
//   WH/WL[nblk8][chunk64][ng4][oct2][n32][k8]   u16
// main: NO LDS, NO barriers. 512 blocks (2/CU) x 256 thr; wave owns a 64x64 quadrant of a
// 128x128 tile over a 16-chunk k-slice. Per chunk: 8 global_load_dwordx4 (frags direct from
// L2; lane*16 contiguous per 1KB sub-plane) prefetched one chunk ahead into a 2-deep register
// buffer + 12 MFMA (AhBh+AlBh+AhBl per 32x32; AlBl dropped, |err|<=4e-6 of rint grid) +
// quant (rndne, med3, add). Waves free-run; latency hidden by depth-1 prefetch + 8 waves/CU.
// Swizzle: bx%8 = ks + 4*(mblk&1) -> per-XCD working set ~2MB (A 1MB + B 1MB) -> L2-resident.
// R5 failure mode removed: no vmcnt(0)+s_barrier stage drain (the m97-plateau stall).
// Integer partials to ws; reduce4: out = 16*(p0+p1+p2+p3).

typedef unsigned int u32;
typedef unsigned short u16;
typedef _Float16 f16x8 __attribute__((ext_vector_type(8)));
typedef float f32x16 __attribute__((ext_vector_type(16)));

#define M_TOT 2048
#define N_TOT 1024
#define K_TOT 1024

__global__ __launch_bounds__(256) void presplit(
    const float* __restrict__ x, const float* __restrict__ w,
    const float* __restrict__ vl, const float* __restrict__ wl,
    u16* __restrict__ XH, u16* __restrict__ XL,
    u16* __restrict__ WH, u16* __restrict__ WL)
{
  const int b = blockIdx.x;
  if (b < 512) {
    // X: lane runs along k (16 consecutive floats); wave covers 4KB contiguous.
    const int g = b * 256 + threadIdx.x;
    const int ch = g & 63, m = g >> 6;
    const int mblk = m >> 7, rg = (m >> 5) & 3, row = m & 31;
    const float* xp = x + (size_t)m * K_TOT + ch * 16;
    u32 hp[8], lp[8];
#pragma unroll
    for (int e2 = 0; e2 < 8; ++e2) {
      u16 h2[2], l2[2];
#pragma unroll
      for (int q = 0; q < 2; ++q) {
        const int e = e2 * 2 + q;
        const float v = xp[e];
        const int xi = (int)(v + 8.0f);          // x always in [-8,7]
        const float a = v + vl[e * 16 + xi];     // j = k%16 = e (chunk-aligned)
        const _Float16 h = (_Float16)a;
        const _Float16 l = (_Float16)(a - (float)h);
        h2[q] = __builtin_bit_cast(u16, h);
        l2[q] = __builtin_bit_cast(u16, l);
      }
      hp[e2] = (u32)h2[0] | ((u32)h2[1] << 16);
      lp[e2] = (u32)l2[0] | ((u32)l2[1] << 16);
    }
    const size_t base = (size_t)(mblk * 64 + ch) * 2048 + rg * 512 + row * 8;
    *(uint4*)&XH[base]       = make_uint4(hp[0], hp[1], hp[2], hp[3]);  // oct0
    *(uint4*)&XH[base + 256] = make_uint4(hp[4], hp[5], hp[6], hp[7]);  // oct1
    *(uint4*)&XL[base]       = make_uint4(lp[0], lp[1], lp[2], lp[3]);
    *(uint4*)&XL[base + 256] = make_uint4(lp[4], lp[5], lp[6], lp[7]);
  } else {
    // W: lane runs along n; k-rows strided. Scale by 1/16 (exact) before split.
    const int g = (b - 512) * 256 + threadIdx.x;
    const int n = g & 1023, ch = g >> 10;
    const int nblk = n >> 7, ng = (n >> 5) & 3, n32 = n & 31;
    const float* wp = w + (size_t)(ch * 16) * N_TOT + n;
    u32 hp[8], lp[8];
#pragma unroll
    for (int e2 = 0; e2 < 8; ++e2) {
      u16 h2[2], l2[2];
#pragma unroll
      for (int q = 0; q < 2; ++q) {
        const int e = e2 * 2 + q;
        const float v = wp[(size_t)e * N_TOT];
        const int wi = (int)(v + 8.0f);
        const float a = (v + wl[e * 16 + wi]) * 0.0625f;  // fold 1/16 into B (exact)
        const _Float16 h = (_Float16)a;
        const _Float16 l = (_Float16)(a - (float)h);
        h2[q] = __builtin_bit_cast(u16, h);
        l2[q] = __builtin_bit_cast(u16, l);
      }
      hp[e2] = (u32)h2[0] | ((u32)h2[1] << 16);
      lp[e2] = (u32)l2[0] | ((u32)l2[1] << 16);
    }
    const size_t base = (size_t)(nblk * 64 + ch) * 2048 + ng * 512 + n32 * 8;
    *(uint4*)&WH[base]       = make_uint4(hp[0], hp[1], hp[2], hp[3]);
    *(uint4*)&WH[base + 256] = make_uint4(hp[4], hp[5], hp[6], hp[7]);
    *(uint4*)&WL[base]       = make_uint4(lp[0], lp[1], lp[2], lp[3]);
    *(uint4*)&WL[base + 256] = make_uint4(lp[4], lp[5], lp[6], lp[7]);
  }
}

__global__ __launch_bounds__(256, 2) void opu_main(
    const u16* __restrict__ XH, const u16* __restrict__ XL,
    const u16* __restrict__ WH, const u16* __restrict__ WL,
    float* __restrict__ partials)
{
  const int tid  = threadIdx.x;
  const int wave = tid >> 6;
  const int lane = tid & 63;
  const int oct  = lane >> 5;
  const int ll   = lane & 31;
  const int wm   = wave >> 1;   // m-half of 128x128 tile (64 rows)
  const int wn   = wave & 1;    // n-half (64 cols)

  // bx%8 = ks + 4*(mblk&1): each XCD sees one ks and one mblk-parity ->
  // A working set 8 mblk-halves... = 1MB, B 8 nblk x 1 ks = 1MB -> L2-resident.
  const int bx   = blockIdx.x;
  const int ks   = bx & 3;
  const int par  = (bx >> 2) & 1;
  const int t6   = bx >> 3;
  const int mblk = (t6 & 7) * 2 + par;  // 0..15
  const int nblk = t6 >> 3;             // 0..7

  const size_t achb = ((size_t)mblk * 64 + ks * 16) * 4096;  // byte offset of chunk 0
  const size_t bchb = ((size_t)nblk * 64 + ks * 16) * 4096;
  const int lb = lane * 16;
  const char* pAh = (const char*)XH + achb + (2 * wm) * 1024 + lb;
  const char* pAl = (const char*)XL + achb + (2 * wm) * 1024 + lb;
  const char* pBh = (const char*)WH + bchb + (2 * wn) * 1024 + lb;
  const char* pBl = (const char*)WL + bchb + (2 * wn) * 1024 + lb;

  uint4 buf[2][8];
#define LOADCH(dst, off)                                   \
  do {                                                     \
    (dst)[0] = *(const uint4*)(pAh + (off));               \
    (dst)[1] = *(const uint4*)(pAh + (off) + 1024);        \
    (dst)[2] = *(const uint4*)(pAl + (off));               \
    (dst)[3] = *(const uint4*)(pAl + (off) + 1024);        \
    (dst)[4] = *(const uint4*)(pBh + (off));               \
    (dst)[5] = *(const uint4*)(pBh + (off) + 1024);        \
    (dst)[6] = *(const uint4*)(pBl + (off));               \
    (dst)[7] = *(const uint4*)(pBl + (off) + 1024);        \
  } while (0)

  LOADCH(buf[0], 0);

  float res[4][16];
#pragma unroll
  for (int t = 0; t < 4; ++t)
#pragma unroll
    for (int i = 0; i < 16; ++i) res[t][i] = 0.0f;
  const f32x16 fzero = {};

#define COMPUTE(c)                                                                      \
  do {                                                                                  \
    f16x8 Ah[2], Al[2], Bh[2], Bl[2];                                                   \
    Ah[0] = __builtin_bit_cast(f16x8, (c)[0]);                                          \
    Ah[1] = __builtin_bit_cast(f16x8, (c)[1]);                                          \
    Al[0] = __builtin_bit_cast(f16x8, (c)[2]);                                          \
    Al[1] = __builtin_bit_cast(f16x8, (c)[3]);                                          \
    Bh[0] = __builtin_bit_cast(f16x8, (c)[4]);                                          \
    Bh[1] = __builtin_bit_cast(f16x8, (c)[5]);                                          \
    Bl[0] = __builtin_bit_cast(f16x8, (c)[6]);                                          \
    Bl[1] = __builtin_bit_cast(f16x8, (c)[7]);                                          \
    _Pragma("unroll")                                                                   \
    for (int mt = 0; mt < 2; ++mt)                                                      \
      _Pragma("unroll")                                                                 \
      for (int nt = 0; nt < 2; ++nt) {                                                  \
        f32x16 acc = __builtin_amdgcn_mfma_f32_32x32x16_f16(Ah[mt], Bh[nt], fzero, 0, 0, 0); \
        acc = __builtin_amdgcn_mfma_f32_32x32x16_f16(Al[mt], Bh[nt], acc, 0, 0, 0);     \
        acc = __builtin_amdgcn_mfma_f32_32x32x16_f16(Ah[mt], Bl[nt], acc, 0, 0, 0);     \
        float* r4 = res[mt * 2 + nt];                                                   \
        _Pragma("unroll")                                                               \
        for (int i = 0; i < 16; ++i) {                                                  \
          float r = __builtin_rintf(acc[i]);               /* acc = mm/16 already */    \
          r = __builtin_amdgcn_fmed3f(r, -128.0f, 127.0f); /* clip */                   \
          r4[i] += r;                                                                   \
        }                                                                               \
      }                                                                                 \
  } while (0)

#pragma unroll 1
  for (int ch2 = 0; ch2 < 8; ++ch2) {
    const size_t o = (size_t)ch2 * 8192;
    LOADCH(buf[1], o + 4096);   // prefetch odd chunk
    COMPUTE(buf[0]);            // compute even chunk
    if (ch2 < 7) LOADCH(buf[0], o + 8192);  // prefetch next even
    COMPUTE(buf[1]);            // compute odd chunk
  }

  // integer-valued partial sums -> ws
  float* pp = partials + (size_t)ks * (M_TOT * N_TOT);
  const int grow = mblk * 128 + wm * 64;
  const int gcol = nblk * 128 + wn * 64 + ll;
#pragma unroll
  for (int mt = 0; mt < 2; ++mt)
#pragma unroll
    for (int nt = 0; nt < 2; ++nt)
#pragma unroll
      for (int i = 0; i < 16; ++i) {
        const int rr = (i & 3) + 8 * (i >> 2) + 4 * oct;  // verified C/D layout
        pp[(size_t)(grow + mt * 32 + rr) * N_TOT + gcol + nt * 32] = res[mt * 2 + nt][i];
      }
}

__global__ __launch_bounds__(256) void reduce4(const float4* __restrict__ p,
                                               float4* __restrict__ out)
{
  const int i = blockIdx.x * 256 + threadIdx.x;     // 512K float4
  const float4 a = p[i];
  const float4 b = p[i + 524288];
  const float4 c = p[i + 2 * 524288];
  const float4 d = p[i + 3 * 524288];
  float4 o;
  o.x = 16.0f * (a.x + b.x + c.x + d.x);
  o.y = 16.0f * (a.y + b.y + c.y + d.y);
  o.z = 16.0f * (a.z + b.z + c.z + d.z);
  o.w = 16.0f * (a.w + b.w + c.w + d.w);
  out[i] = o;
}

extern "C" void kernel_launch(void* const* d_in, const int* in_sizes, int n_in,
                              void* d_out, int out_size, void* d_ws, size_t ws_size,
                              hipStream_t stream)
{
  const float* input  = (const float*)d_in[0];
  const float* weight = (const float*)d_in[1];
  const float* vmap   = (const float*)d_in[2];
  const float* wmap   = (const float*)d_in[3];

  u16* XH = (u16*)d_ws;                          // 4MB (2M u16)
  u16* XL = XH + 2 * 1024 * 1024;                // 4MB
  u16* WH = XL + 2 * 1024 * 1024;                // 2MB
  u16* WL = WH + 1024 * 1024;                    // 2MB
  float* partials = (float*)((char*)d_ws + 12 * 1024 * 1024);  // 4 x 8MB

  presplit<<<768, 256, 0, stream>>>(input, weight, vmap, wmap, XH, XL, WH, WL);

  opu_main<<<512, 256, 0, stream>>>(XH, XL, WH, WL, partials);

  reduce4<<<2048, 256, 0, stream>>>((const float4*)partials, (float4*)d_out);
}